// Round 3
// baseline (753.126 us; speedup 1.0000x reference)
//
#include <hip/hip_runtime.h>
#include <hip/hip_bf16.h>
#include <stdint.h>

using bf16 = __hip_bfloat16;

typedef short bf16x8 __attribute__((ext_vector_type(8)));
typedef float f32x4 __attribute__((ext_vector_type(4)));

__device__ __forceinline__ float bf2f(bf16 x) { return __bfloat162float(x); }
__device__ __forceinline__ bf16 f2bf(float x) { return __float2bfloat16(x); }

// Async global->LDS, 16B per lane. LDS destination is wave-uniform base +
// lane*16 (m104); global source IS per-lane (so swizzle goes on the source).
__device__ __forceinline__ void async_load16(const bf16* gptr, bf16* lptr) {
    __builtin_amdgcn_global_load_lds(
        (const __attribute__((address_space(1))) void*)gptr,
        (__attribute__((address_space(3))) void*)lptr,
        16, 0, 0);
}

// Raw barrier (no implicit vmcnt(0) drain) + compiler memory fences.
__device__ __forceinline__ void wg_barrier() {
    asm volatile("" ::: "memory");
    __builtin_amdgcn_s_barrier();
    asm volatile("" ::: "memory");
}

#define VMCNT(n) asm volatile("s_waitcnt vmcnt(" #n ")" ::: "memory")

// ---------------------------------------------------------------------------
// 256x128xK GEMM, 4-wave workgroup, TWO workgroups per CU (R3 change).
// C[m,n] = sum_k A[m,k] * Bt[n,k]   (A: MxK row-major, Bt: NxK row-major)
// MODE 0: bf16 (acc+bias) | MODE 1: bf16 sigmoid(acc+bias) | MODE 2: f32
//
// R2 post-mortem: one 8-wave/128KiB block per CU => every barrier/vmcnt
// stall idles the whole CU (MfmaUtil 42%). Fix: 64 KiB LDS + 4-wave blocks
// -> 2 independent blocks/CU; one block's MFMA covers the other's stalls.
//
// LDS (64 KiB, single-buffered except Ahi which has 2 slots):
//   A pairs p=0..15  (16 rows x 64k each, as 2x 512-elem subtiles) @ p*1024
//   B pairs p=0..7                                     @ 16384 + p*1024
//   Ahi slot1 (pairs {4..7,12..15}, compact ci)        @ 24576 + ci*1024
// Subtile swizzle s(o) = o ^ (((o>>7)&3)<<4) (involution): inverse-permuted
// global source + permuted read offset -> 2 lanes/bank on ds_read (free).
//
// 4-region loop per K-tile t (one barrier per region; barrier semantics put
// all waves of a block in the same region, so stage-in-region-(n+1) strictly
// follows reads-in-region-n):
//  R2: MFMA(0,0)      ; read Bhi(t)                         ; bar
//  R3: stage Ahi(t+1)->slot~ , Alo(t+1), Blo(t+1) [10 loads];
//      MFMA(0,1)      ; read Ahi(t) slot                    ; bar
//  R4: stage Bhi(t+1) [2]; MFMA(1,1); VMCNT(2)              ; bar
//        (drains Ahi',Alo',Blo' -> R1 reads safe; leaves Bhi' in flight)
//  R1: MFMA(1,0)      ; read Alo,Blo(t+1); VMCNT(0)         ; bar
//        (drains Bhi', issued 1.5 regions earlier -> cheap)
// Region overwrite safety: Alo/Blo staged R3(t), last read R1(t) (1 full
// barrier earlier) OK; Bhi staged R4(t), read R2(t) OK; Ahi(t+1) goes to the
// other slot, last read R3(t-1) OK.
// ---------------------------------------------------------------------------
template <int MODE>
__global__ __launch_bounds__(256, 2) void gemm256(
    const bf16* __restrict__ A, const bf16* __restrict__ Bt,
    const float* __restrict__ bias, void* __restrict__ Cout,
    int M, int N, int K)
{
    __shared__ bf16 lds[32768];   // 64 KiB

    const int tid  = threadIdx.x;
    const int wid  = tid >> 6;    // 0..3
    const int lane = tid & 63;
    const int wm = wid >> 1;      // 0..1 (row half)
    const int wn = wid & 1;       // 0..1 (col half)

    // T1: bijective XCD-aware block swizzle (m204 form)
    const int nwg = gridDim.x;
    const int q8 = nwg >> 3, r8 = nwg & 7;
    const int xcd = blockIdx.x & 7, loc = blockIdx.x >> 3;
    const int wgid = (xcd < r8 ? xcd * (q8 + 1) : r8 * (q8 + 1) + (xcd - r8) * q8) + loc;
    const int ntn = N >> 7;
    const int bx = wgid % ntn;
    const int by = wgid / ntn;
    const int m0 = by * 256;
    const int n0 = bx * 128;

    const bf16* Ablk = A  + (size_t)m0 * K;
    const bf16* Bblk = Bt + (size_t)n0 * K;

    // fragment read decode (16x16x32: A[m=lane&15][k=(lane>>4)*8+j])
    const int frow = lane & 15;
    const int fq   = lane >> 4;
    // swizzled element offset within a 512-elem subtile (16B-aligned)
    const int roff = frow * 32 + ((fq ^ ((frow >> 1) & 3)) * 8);

    // staging source decode: lane' = lane ^ ((lane>>3)&3) (inverse of s())
    const int swl  = lane ^ ((lane >> 3) & 3);
    const int srow = swl >> 2;
    const int scol = (swl & 3) * 8;

    // stage A: wave covers region-relative pairs r = wid*2, wid*2+1
    //   pair p = (r&3) + q*4 + ((r>>2)<<3)
    auto stageA = [&](int k0, int q, int slot) {
#pragma unroll
        for (int rr = 0; rr < 2; ++rr) {
            const int r = wid * 2 + rr;
            const int p = (r & 3) + q * 4 + ((r >> 2) << 3);
            const bf16* g = Ablk + (size_t)(p * 16 + srow) * K + (k0 + scol);
            bf16* l = (q == 1 && slot) ? &lds[24576 + r * 1024] : &lds[p * 1024];
            async_load16(g, l);
            async_load16(g + 32, l + 512);
        }
    };
    // stage B: wave covers pair p = (wid&1) + ((wid>>1)<<2) + q*2
    auto stageB = [&](int k0, int q) {
        const int p = (wid & 1) + ((wid >> 1) << 2) + q * 2;
        const bf16* g = Bblk + (size_t)(p * 16 + srow) * K + (k0 + scol);
        bf16* l = &lds[16384 + p * 1024];
        async_load16(g, l);
        async_load16(g + 32, l + 512);
    };

    f32x4 acc[8][4];
#pragma unroll
    for (int i = 0; i < 8; ++i)
#pragma unroll
        for (int j = 0; j < 4; ++j)
            acc[i][j] = f32x4{0.f, 0.f, 0.f, 0.f};

    bf16x8 af[4][2];      // current ih half: 4 row-frags x 2 k-substeps
    bf16x8 bfr[2][2][2];  // both jh halves resident: [jh][j][kk]

    auto LDA0 = [&]() {   // Alo: pairs wm*8 + i
#pragma unroll
        for (int i = 0; i < 4; ++i)
#pragma unroll
            for (int kk = 0; kk < 2; ++kk)
                af[i][kk] = *(const bf16x8*)&lds[(wm * 8 + i) * 1024 + kk * 512 + roff];
    };
    auto LDA1 = [&](int slot) {  // Ahi: pairs wm*8+4+i (slot1 compact: wm*4+i)
#pragma unroll
        for (int i = 0; i < 4; ++i) {
            const int base = slot ? (24576 + (wm * 4 + i) * 1024)
                                  : ((wm * 8 + 4 + i) * 1024);
#pragma unroll
            for (int kk = 0; kk < 2; ++kk)
                af[i][kk] = *(const bf16x8*)&lds[base + kk * 512 + roff];
        }
    };
    auto LDB = [&](int jh) {     // pairs wn*4 + jh*2 + j
#pragma unroll
        for (int j = 0; j < 2; ++j)
#pragma unroll
            for (int kk = 0; kk < 2; ++kk)
                bfr[jh][j][kk] = *(const bf16x8*)&lds[16384 +
                    (wn * 4 + jh * 2 + j) * 1024 + kk * 512 + roff];
    };
    auto MFMAQ = [&](int ih, int jh) {
        __builtin_amdgcn_s_setprio(1);
#pragma unroll
        for (int kk = 0; kk < 2; ++kk)
#pragma unroll
            for (int i = 0; i < 4; ++i)
#pragma unroll
                for (int j = 0; j < 2; ++j)
                    acc[ih * 4 + i][jh * 2 + j] =
                        __builtin_amdgcn_mfma_f32_16x16x32_bf16(
                            af[i][kk], bfr[jh][j][kk],
                            acc[ih * 4 + i][jh * 2 + j], 0, 0, 0);
        __builtin_amdgcn_s_setprio(0);
    };

    const int NT = K >> 6;   // K/64: 16 or 32

    // ---- prologue: tile 0 (Ahi->slot0, Alo, Blo, Bhi = 12 loads/wave)
    stageA(0, 1, 0);   // Ahi(0) slot0 [4]
    stageA(0, 0, 0);   // Alo(0)       [4]
    stageB(0, 0);      // Blo(0)       [2]
    stageB(0, 1);      // Bhi(0)       [2]
    VMCNT(2);          // drain Ahi,Alo,Blo; Bhi in flight
    wg_barrier();
    // R1(0): reads for quad (0,0)
    LDA0(); LDB(0);
    VMCNT(0);          // drain Bhi(0) (needed in R2)
    wg_barrier();

    for (int t = 0; t < NT; ++t) {
        const int kn = (t + 1 < NT ? t + 1 : NT - 1) << 6;  // clamped (dead)
        const int sl = (t + 1) & 1;
        // R2
        MFMAQ(0, 0);
        LDB(1);                 // Bhi(t)
        wg_barrier();
        // R3
        stageA(kn, 1, sl);      // Ahi(t+1) -> other slot [4]
        stageA(kn, 0, 0);       // Alo(t+1)               [4]
        stageB(kn, 0);          // Blo(t+1)               [2]
        MFMAQ(0, 1);
        LDA1(t & 1);            // Ahi(t)
        wg_barrier();
        // R4
        stageB(kn, 1);          // Bhi(t+1)               [2]
        MFMAQ(1, 1);
        VMCNT(2);               // drain Ahi',Alo',Blo'; leave Bhi'
        wg_barrier();
        // R1(t+1)
        MFMAQ(1, 0);
        LDA0(); LDB(0);         // tile t+1 (last iter: dead clamped data)
        VMCNT(0);               // drain Bhi' (1.5 regions of slack)
        wg_barrier();
    }

    // C/D layout (verified m89/m91): col = lane&15, row = (lane>>4)*4 + reg.
    // j innermost: 4 back-to-back stores = 64 contiguous cols per row
    // (write-combining; R2 confirmed WRITE_SIZE at ideal).
    const int crow = fq * 4;
    const int ccol = frow;
    float bv[4];
#pragma unroll
    for (int j = 0; j < 4; ++j) bv[j] = bias[n0 + wn * 64 + 16 * j + ccol];
#pragma unroll
    for (int i = 0; i < 8; ++i) {
#pragma unroll
        for (int r = 0; r < 4; ++r) {
            const int row = m0 + wm * 128 + 16 * i + crow + r;
#pragma unroll
            for (int j = 0; j < 4; ++j) {
                const int col = n0 + wn * 64 + 16 * j + ccol;
                float v = acc[i][j][r] + bv[j];
                if constexpr (MODE == 1) v = 1.f / (1.f + __expf(-v));
                if constexpr (MODE == 2)
                    ((float*)Cout)[(size_t)row * N + col] = v;
                else
                    ((bf16*)Cout)[(size_t)row * N + col] = f2bf(v);
            }
        }
    }
}

// ---------------- scan: h_t = a*h_{t-1} + u_t ; s_t = h_t * g_t -------------
// a = sigmoid(log_a) <= ~0.4 => a^64 < 1e-25: chunk T with 64-step warm-up
// from zero state, no cross-chunk communication. s written in place over g.
#define SCAN_T 4096
#define SCAN_H 2048
#define SCAN_B 8
#define SCAN_L 512
#define SCAN_W 64

__global__ __launch_bounds__(256) void lru_scan(
    const bf16* __restrict__ u, bf16* gs, const float* __restrict__ asig)
{
    const int tid   = blockIdx.x * 256 + threadIdx.x;
    const int h     = tid & (SCAN_H - 1);
    const int rem   = tid >> 11;              // H = 2048 = 2^11
    const int b     = rem & (SCAN_B - 1);
    const int chunk = rem >> 3;               // 0..7

    const float a = asig[h];
    const size_t base = (size_t)b * SCAN_T * SCAN_H + h;
    const bf16* up = u + base;
    bf16* gp = gs + base;

    const int t1 = chunk * SCAN_L;
    const int warm0 = (chunk == 0) ? 0 : SCAN_W;

    float hs = 0.f;
    for (int t = t1 - warm0; t < t1; t += 8) {
        float uv[8];
#pragma unroll
        for (int i = 0; i < 8; ++i) uv[i] = bf2f(up[(size_t)(t + i) * SCAN_H]);
#pragma unroll
        for (int i = 0; i < 8; ++i) hs = fmaf(a, hs, uv[i]);
    }
    for (int t = t1; t < t1 + SCAN_L; t += 8) {
        float uv[8], gv[8];
#pragma unroll
        for (int i = 0; i < 8; ++i) {
            uv[i] = bf2f(up[(size_t)(t + i) * SCAN_H]);
            gv[i] = bf2f(gp[(size_t)(t + i) * SCAN_H]);
        }
#pragma unroll
        for (int i = 0; i < 8; ++i) {
            hs = fmaf(a, hs, uv[i]);
            gp[(size_t)(t + i) * SCAN_H] = f2bf(hs * gv[i]);
        }
    }
}

// ---------------- converts / prep ----------------
__global__ void cvt_f32_bf16_x4(const float* __restrict__ in,
                                bf16* __restrict__ out, int n4)
{
    const int i = blockIdx.x * blockDim.x + threadIdx.x;
    if (i >= n4) return;
    const float4 v = ((const float4*)in)[i];
    bf16 h[4] __attribute__((aligned(8)));
    h[0] = f2bf(v.x); h[1] = f2bf(v.y); h[2] = f2bf(v.z); h[3] = f2bf(v.w);
    ((uint64_t*)out)[i] = *(const uint64_t*)h;
}

__global__ void sigmoid_vec(const float* __restrict__ in,
                            float* __restrict__ out, int n)
{
    const int i = blockIdx.x * blockDim.x + threadIdx.x;
    if (i < n) out[i] = 1.f / (1.f + __expf(-in[i]));
}

// ---------------- launch ----------------
extern "C" void kernel_launch(void* const* d_in, const int* in_sizes, int n_in,
                              void* d_out, int out_size, void* d_ws, size_t ws_size,
                              hipStream_t stream)
{
    const float* x     = (const float*)d_in[0];
    const float* Wi    = (const float*)d_in[1];
    const float* bi    = (const float*)d_in[2];
    const float* Wg    = (const float*)d_in[3];
    const float* bg    = (const float*)d_in[4];
    const float* Wo    = (const float*)d_in[5];
    const float* bo    = (const float*)d_in[6];
    const float* log_a = (const float*)d_in[7];
    float* y = (float*)d_out;

    constexpr int Bc = 8, T = 4096, DIN = 1024, H = 2048;
    constexpr int M = Bc * T;   // 32768

    char* ws = (char*)d_ws;
    size_t off = 0;
    auto alloc = [&](size_t bytes) -> void* {
        void* p = ws + off;
        off += (bytes + 255) & ~(size_t)255;
        return p;
    };
    bf16*  xb   = (bf16*)alloc((size_t)M * DIN * 2);    // 67.1 MB
    bf16*  wib  = (bf16*)alloc((size_t)H * DIN * 2);    // 4.2 MB
    bf16*  wgb  = (bf16*)alloc((size_t)H * DIN * 2);    // 4.2 MB
    bf16*  wob  = (bf16*)alloc((size_t)DIN * H * 2);    // 4.2 MB
    float* asig = (float*)alloc((size_t)H * 4);
    bf16*  u    = (bf16*)alloc((size_t)M * H * 2);      // 134.2 MB
    bf16*  g    = (bf16*)alloc((size_t)M * H * 2);      // 134.2 MB (becomes s)
    (void)ws_size; (void)in_sizes; (void)n_in; (void)out_size;

    // converts
    {
        const int n4 = M * DIN / 4;
        cvt_f32_bf16_x4<<<(n4 + 255) / 256, 256, 0, stream>>>(x, xb, n4);
        const int w4 = H * DIN / 4;
        cvt_f32_bf16_x4<<<(w4 + 255) / 256, 256, 0, stream>>>(Wi, wib, w4);
        cvt_f32_bf16_x4<<<(w4 + 255) / 256, 256, 0, stream>>>(Wg, wgb, w4);
        cvt_f32_bf16_x4<<<(w4 + 255) / 256, 256, 0, stream>>>(Wo, wob, w4);
        sigmoid_vec<<<(H + 255) / 256, 256, 0, stream>>>(log_a, asig, H);
    }

    // u = x Wi^T + bi   (bf16 out)
    gemm256<0><<<(M / 256) * (H / 128), 256, 0, stream>>>(xb, wib, bi, u, M, H, DIN);
    // g = sigmoid(x Wg^T + bg)   (bf16 out)
    gemm256<1><<<(M / 256) * (H / 128), 256, 0, stream>>>(xb, wgb, bg, g, M, H, DIN);

    // scan + gate multiply, in place over g
    lru_scan<<<(Bc * H * (T / SCAN_L)) / 256, 256, 0, stream>>>(u, g, asig);

    // y = s Wo^T + bo   (f32 out)
    gemm256<2><<<(M / 256) * (DIN / 128), 256, 0, stream>>>(g, wob, bo, y, M, DIN, H);
}

// Round 4
// 749.894 us; speedup vs baseline: 1.0043x; 1.0043x over previous
//
#include <hip/hip_runtime.h>
#include <hip/hip_bf16.h>
#include <stdint.h>

using bf16 = __hip_bfloat16;

typedef short bf16x8 __attribute__((ext_vector_type(8)));
typedef float f32x4 __attribute__((ext_vector_type(4)));

__device__ __forceinline__ float bf2f(bf16 x) { return __bfloat162float(x); }
__device__ __forceinline__ bf16 f2bf(float x) { return __float2bfloat16(x); }

// Async global->LDS, 16B per lane. LDS destination is wave-uniform base +
// lane*16 (m104); global source IS per-lane (so swizzle goes on the source).
__device__ __forceinline__ void async_load16(const bf16* gptr, bf16* lptr) {
    __builtin_amdgcn_global_load_lds(
        (const __attribute__((address_space(1))) void*)gptr,
        (__attribute__((address_space(3))) void*)lptr,
        16, 0, 0);
}

// Raw barrier (no implicit vmcnt(0) drain) + compiler memory fences.
__device__ __forceinline__ void wg_barrier() {
    asm volatile("" ::: "memory");
    __builtin_amdgcn_s_barrier();
    asm volatile("" ::: "memory");
}

#define VMCNT(n) asm volatile("s_waitcnt vmcnt(" #n ")" ::: "memory")

// ---------------------------------------------------------------------------
// 256x256xK GEMM, 8 waves, full LDS double-buffer, ONE barrier per K-tile.
// C[m,n] = sum_k A[m,k] * Bt[n,k]   (A: MxK row-major, Bt: NxK row-major)
// MODE 0: bf16 (acc+bias) | MODE 1: bf16 sigmoid(acc+bias) | MODE 2: f32
//
// R3 post-mortem: per-phase barriers kept all waves PHASE-ALIGNED -> matrix
// (621 cyc) and LDS (~700 cyc) bursts alternated, fully additive
// (measured 1377 cyc/phase = 621+700+sync, exactly). Fix: one barrier per
// K-tile (~2800-cyc region). Within the region waves drift, so one wave's
// MFMA overlaps another's ds_reads (m114 mechanism). Overlapped floor =
// max(matrix 2484, LDS 2800) ~= 3100 cyc/K-tile vs R2's 5509.
//
// LDS (128 KiB): buf p @ p*32768 elems; A pairs 0..15 @ rg*1024, B pairs
// 0..15 @ 16384+rg*1024 (each pair = 16 rows x 64 k = 2 KB, two 512-elem
// subtiles). Subtile swizzle s(o) = o ^ (((o>>7)&3)<<4) (involution):
// inverse-permuted global source + permuted read offset -> 2 lanes/bank on
// ds_read (free; R2 measured 0 conflicts).
//
// Region R_t (between barriers):  reads buf[t&1] only; stages buf[(t+1)&1]
// only (standard dbuf ledger: buffer staged in R_t was last read in R_{t-1},
// separated by the entry barrier). VMCNT(0) at region END drains this
// wave's 8 stage loads (issued near region start => ~full-region slack,
// ~3000 cyc >> 900-cyc HBM latency); the barrier then publishes to readers.
// No vmcnt inside the compute stream; no per-phase barriers.
// ---------------------------------------------------------------------------
template <int MODE>
__global__ __launch_bounds__(512, 2) void gemm256(
    const bf16* __restrict__ A, const bf16* __restrict__ Bt,
    const float* __restrict__ bias, void* __restrict__ Cout,
    int M, int N, int K)
{
    __shared__ bf16 lds[2 * 32768];   // 128 KiB

    const int tid  = threadIdx.x;
    const int wid  = tid >> 6;
    const int lane = tid & 63;
    const int wm = wid >> 2;     // 0..1
    const int wn = wid & 3;      // 0..3

    // T1: bijective XCD-aware block swizzle (m204 form)
    const int nwg = gridDim.x;
    const int q8 = nwg >> 3, r8 = nwg & 7;
    const int xcd = blockIdx.x & 7, loc = blockIdx.x >> 3;
    const int wgid = (xcd < r8 ? xcd * (q8 + 1) : r8 * (q8 + 1) + (xcd - r8) * q8) + loc;
    const int ntn = N >> 8;
    const int bx = wgid % ntn;
    const int by = wgid / ntn;
    const int m0 = by * 256;
    const int n0 = bx * 256;

    const bf16* Ablk = A  + (size_t)m0 * K;
    const bf16* Bblk = Bt + (size_t)n0 * K;

    // fragment read decode (16x16x32: A[m=lane&15][k=(lane>>4)*8+j])
    const int frow = lane & 15;
    const int fq   = lane >> 4;
    // swizzled element offset within a 512-elem subtile (16B-aligned)
    const int roff = frow * 32 + ((fq ^ ((frow >> 1) & 3)) * 8);

    // staging source decode: lane' = lane ^ ((lane>>3)&3) (inverse of s())
    const int swl  = lane ^ ((lane >> 3) & 3);
    const int srow = swl >> 2;
    const int scol = (swl & 3) * 8;

    // wave -> subtile-row-group for quarter staging
    const int rgA = (wid & 3) + ((wid & 4) << 1);                    // +q*4
    const int rgB = (wid & 1) + ((wid & 2) << 1) + ((wid & 4) << 1); // +q*2

    auto stageA = [&](int buf, int k0, int q) {
        const int rg = rgA + q * 4;
        const bf16* g = Ablk + (size_t)(rg * 16 + srow) * K + (k0 + scol);
        bf16* l = &lds[buf * 32768 + rg * 1024];
        async_load16(g, l);            // cg=0
        async_load16(g + 32, l + 512); // cg=1
    };
    auto stageB = [&](int buf, int k0, int q) {
        const int rg = rgB + q * 2;
        const bf16* g = Bblk + (size_t)(rg * 16 + srow) * K + (k0 + scol);
        bf16* l = &lds[buf * 32768 + 16384 + rg * 1024];
        async_load16(g, l);
        async_load16(g + 32, l + 512);
    };

    f32x4 acc[8][4];
#pragma unroll
    for (int i = 0; i < 8; ++i)
#pragma unroll
        for (int j = 0; j < 4; ++j)
            acc[i][j] = f32x4{0.f, 0.f, 0.f, 0.f};

    bf16x8 af[4][2];      // current ih half: 4 row-frags x 2 k-substeps
    bf16x8 bfr[2][2][2];  // both jh halves resident: [jh][j][kk]

    auto LDA = [&](int buf, int ih) {
#pragma unroll
        for (int i = 0; i < 4; ++i)
#pragma unroll
            for (int kk = 0; kk < 2; ++kk)
                af[i][kk] = *(const bf16x8*)&lds[buf * 32768 +
                    ((wm * 8 + ih * 4 + i) * 2 + kk) * 512 + roff];
    };
    auto LDB = [&](int buf, int jh) {
#pragma unroll
        for (int j = 0; j < 2; ++j)
#pragma unroll
            for (int kk = 0; kk < 2; ++kk)
                bfr[jh][j][kk] = *(const bf16x8*)&lds[buf * 32768 + 16384 +
                    ((wn * 4 + jh * 2 + j) * 2 + kk) * 512 + roff];
    };
    auto MFMAQ = [&](int ih, int jh) {
        __builtin_amdgcn_s_setprio(1);
#pragma unroll
        for (int kk = 0; kk < 2; ++kk)
#pragma unroll
            for (int i = 0; i < 4; ++i)
#pragma unroll
                for (int j = 0; j < 2; ++j)
                    acc[ih * 4 + i][jh * 2 + j] =
                        __builtin_amdgcn_mfma_f32_16x16x32_bf16(
                            af[i][kk], bfr[jh][j][kk],
                            acc[ih * 4 + i][jh * 2 + j], 0, 0, 0);
        __builtin_amdgcn_s_setprio(0);
    };

    const int NT = K >> 6;   // K/64: 16 or 32

    // ---- prologue: stage tile 0 -> buf0 (8 loads/wave), publish
    stageA(0, 0, 0);
    stageA(0, 0, 1);
    stageB(0, 0, 0);
    stageB(0, 0, 1);
    VMCNT(0);
    wg_barrier();

    for (int t = 0; t < NT; ++t) {
        const int p  = t & 1;
        const int kn = (t + 1 < NT ? t + 1 : NT - 1) << 6;  // clamped (dead)
        // reads for q(0,*) first (MFMA needs them soonest)
        LDA(p, 0); LDB(p, 0); LDB(p, 1);
        // stage next tile into the other buffer (8 loads; drained at region end)
        stageA(p ^ 1, kn, 0);
        stageA(p ^ 1, kn, 1);
        stageB(p ^ 1, kn, 0);
        stageB(p ^ 1, kn, 1);
        MFMAQ(0, 0);
        MFMAQ(0, 1);
        LDA(p, 1);           // Ahi; WAR on af handled in-order after q(0,*)
        MFMAQ(1, 1);
        MFMAQ(1, 0);
        VMCNT(0);            // drain own stage loads (~full region of slack)
        wg_barrier();        // publish buf p^1; all waves done reading buf p
    }

    // C/D layout (verified m89/m91): col = lane&15, row = (lane>>4)*4 + reg.
    // j innermost: 4 back-to-back stores = 64 contiguous cols per row
    // (write-combining; R2 confirmed WRITE_SIZE at ideal 131 MB).
    const int crow = fq * 4;
    const int ccol = frow;
    float bv[4];
#pragma unroll
    for (int j = 0; j < 4; ++j) bv[j] = bias[n0 + wn * 64 + 16 * j + ccol];
#pragma unroll
    for (int i = 0; i < 8; ++i) {
#pragma unroll
        for (int r = 0; r < 4; ++r) {
            const int row = m0 + wm * 128 + 16 * i + crow + r;
#pragma unroll
            for (int j = 0; j < 4; ++j) {
                const int col = n0 + wn * 64 + 16 * j + ccol;
                float v = acc[i][j][r] + bv[j];
                if constexpr (MODE == 1) v = 1.f / (1.f + __expf(-v));
                if constexpr (MODE == 2)
                    ((float*)Cout)[(size_t)row * N + col] = v;
                else
                    ((bf16*)Cout)[(size_t)row * N + col] = f2bf(v);
            }
        }
    }
}

// ---------------- scan: h_t = a*h_{t-1} + u_t ; s_t = h_t * g_t -------------
// a = sigmoid(log_a) <= ~0.4 => a^64 < 1e-25: chunk T with 64-step warm-up
// from zero state, no cross-chunk communication. s written in place over g.
#define SCAN_T 4096
#define SCAN_H 2048
#define SCAN_B 8
#define SCAN_L 512
#define SCAN_W 64

__global__ __launch_bounds__(256) void lru_scan(
    const bf16* __restrict__ u, bf16* gs, const float* __restrict__ asig)
{
    const int tid   = blockIdx.x * 256 + threadIdx.x;
    const int h     = tid & (SCAN_H - 1);
    const int rem   = tid >> 11;              // H = 2048 = 2^11
    const int b     = rem & (SCAN_B - 1);
    const int chunk = rem >> 3;               // 0..7

    const float a = asig[h];
    const size_t base = (size_t)b * SCAN_T * SCAN_H + h;
    const bf16* up = u + base;
    bf16* gp = gs + base;

    const int t1 = chunk * SCAN_L;
    const int warm0 = (chunk == 0) ? 0 : SCAN_W;

    float hs = 0.f;
    for (int t = t1 - warm0; t < t1; t += 8) {
        float uv[8];
#pragma unroll
        for (int i = 0; i < 8; ++i) uv[i] = bf2f(up[(size_t)(t + i) * SCAN_H]);
#pragma unroll
        for (int i = 0; i < 8; ++i) hs = fmaf(a, hs, uv[i]);
    }
    for (int t = t1; t < t1 + SCAN_L; t += 8) {
        float uv[8], gv[8];
#pragma unroll
        for (int i = 0; i < 8; ++i) {
            uv[i] = bf2f(up[(size_t)(t + i) * SCAN_H]);
            gv[i] = bf2f(gp[(size_t)(t + i) * SCAN_H]);
        }
#pragma unroll
        for (int i = 0; i < 8; ++i) {
            hs = fmaf(a, hs, uv[i]);
            gp[(size_t)(t + i) * SCAN_H] = f2bf(hs * gv[i]);
        }
    }
}

// ---------------- converts / prep ----------------
__global__ void cvt_f32_bf16_x4(const float* __restrict__ in,
                                bf16* __restrict__ out, int n4)
{
    const int i = blockIdx.x * blockDim.x + threadIdx.x;
    if (i >= n4) return;
    const float4 v = ((const float4*)in)[i];
    bf16 h[4] __attribute__((aligned(8)));
    h[0] = f2bf(v.x); h[1] = f2bf(v.y); h[2] = f2bf(v.z); h[3] = f2bf(v.w);
    ((uint64_t*)out)[i] = *(const uint64_t*)h;
}

__global__ void sigmoid_vec(const float* __restrict__ in,
                            float* __restrict__ out, int n)
{
    const int i = blockIdx.x * blockDim.x + threadIdx.x;
    if (i < n) out[i] = 1.f / (1.f + __expf(-in[i]));
}

// ---------------- launch ----------------
extern "C" void kernel_launch(void* const* d_in, const int* in_sizes, int n_in,
                              void* d_out, int out_size, void* d_ws, size_t ws_size,
                              hipStream_t stream)
{
    const float* x     = (const float*)d_in[0];
    const float* Wi    = (const float*)d_in[1];
    const float* bi    = (const float*)d_in[2];
    const float* Wg    = (const float*)d_in[3];
    const float* bg    = (const float*)d_in[4];
    const float* Wo    = (const float*)d_in[5];
    const float* bo    = (const float*)d_in[6];
    const float* log_a = (const float*)d_in[7];
    float* y = (float*)d_out;

    constexpr int Bc = 8, T = 4096, DIN = 1024, H = 2048;
    constexpr int M = Bc * T;   // 32768

    char* ws = (char*)d_ws;
    size_t off = 0;
    auto alloc = [&](size_t bytes) -> void* {
        void* p = ws + off;
        off += (bytes + 255) & ~(size_t)255;
        return p;
    };
    bf16*  xb   = (bf16*)alloc((size_t)M * DIN * 2);    // 67.1 MB
    bf16*  wib  = (bf16*)alloc((size_t)H * DIN * 2);    // 4.2 MB
    bf16*  wgb  = (bf16*)alloc((size_t)H * DIN * 2);    // 4.2 MB
    bf16*  wob  = (bf16*)alloc((size_t)DIN * H * 2);    // 4.2 MB
    float* asig = (float*)alloc((size_t)H * 4);
    bf16*  u    = (bf16*)alloc((size_t)M * H * 2);      // 134.2 MB
    bf16*  g    = (bf16*)alloc((size_t)M * H * 2);      // 134.2 MB (becomes s)
    (void)ws_size; (void)in_sizes; (void)n_in; (void)out_size;

    // converts
    {
        const int n4 = M * DIN / 4;
        cvt_f32_bf16_x4<<<(n4 + 255) / 256, 256, 0, stream>>>(x, xb, n4);
        const int w4 = H * DIN / 4;
        cvt_f32_bf16_x4<<<(w4 + 255) / 256, 256, 0, stream>>>(Wi, wib, w4);
        cvt_f32_bf16_x4<<<(w4 + 255) / 256, 256, 0, stream>>>(Wg, wgb, w4);
        cvt_f32_bf16_x4<<<(w4 + 255) / 256, 256, 0, stream>>>(Wo, wob, w4);
        sigmoid_vec<<<(H + 255) / 256, 256, 0, stream>>>(log_a, asig, H);
    }

    // u = x Wi^T + bi   (bf16 out)
    gemm256<0><<<(M / 256) * (H / 256), 512, 0, stream>>>(xb, wib, bi, u, M, H, DIN);
    // g = sigmoid(x Wg^T + bg)   (bf16 out)
    gemm256<1><<<(M / 256) * (H / 256), 512, 0, stream>>>(xb, wgb, bg, g, M, H, DIN);

    // scan + gate multiply, in place over g
    lru_scan<<<(Bc * H * (T / SCAN_L)) / 256, 256, 0, stream>>>(u, g, asig);

    // y = s Wo^T + bo   (f32 out)
    gemm256<2><<<(M / 256) * (DIN / 256), 512, 0, stream>>>(g, wob, bo, y, M, DIN, H);
}